// Round 9
// baseline (208.631 us; speedup 1.0000x reference)
//
#include <hip/hip_runtime.h>
#include <math.h>
#include <stdint.h>

#define F_INN 128
#define HIDD 64
#define ALPHA 0.2f

typedef float v4f  __attribute__((ext_vector_type(4)));
typedef float v2f  __attribute__((ext_vector_type(2)));
typedef short s8v  __attribute__((ext_vector_type(8)));

__device__ __forceinline__ float wave_sum(float v) {
    #pragma unroll
    for (int m = 32; m >= 1; m >>= 1) v += __shfl_xor(v, m, 64);
    return v;
}
// fp32 -> bf16 (RNE) and back
__device__ __forceinline__ unsigned short f2bf(float f) {
    unsigned u = __float_as_uint(f);
    return (unsigned short)((u + 0x7FFFu + ((u >> 16) & 1u)) >> 16);
}
__device__ __forceinline__ float bf2f(unsigned short h) {
    return __uint_as_float(((unsigned)h) << 16);
}
// unpack 2 bf16 (packed in a uint) -> v2f  (2 VALU)
__device__ __forceinline__ v2f unpk(unsigned u) {
    const uint2 t = make_uint2(u << 16, u & 0xFFFF0000u);
    v2f r; r.x = __uint_as_float(t.x); r.y = __uint_as_float(t.y);
    return r;
}

// K01 (merged k02+k1): per-kernel graph overhead measured at ~25-35us each
// (residual constant ~139 across all 3-kernel configs, +33 when a 4th kernel
// was added regardless of its internals) — so kernel COUNT is the lever.
// Feat blocks [0, nFeat): pack W into per-block LDS (removes the pack->feat
// cross-kernel dependency; W is 32KB L2-hot), then the proven k1 MFMA body
// reading B-frags from LDS. Scatter blocks [nFeat, ...): rptr boundary
// scatter, 16 edges/thread (R7-verified code, independent of the pack).
__global__ __launch_bounds__(256) void k01_feat(
    const float* __restrict__ seq, const float* __restrict__ W,
    const float* __restrict__ a1, const float* __restrict__ a2,
    const float* __restrict__ b1, const float* __restrict__ b2,
    const int* __restrict__ erow,
    unsigned short* __restrict__ fts16, float* __restrict__ f1,
    float* __restrict__ f2, int* __restrict__ rptr,
    int n, int E, int nFeat)
{
    const int b = blockIdx.x;
    const int tid = threadIdx.x;

    if (b >= nFeat) {
        // ---- scatter role: rptr[r] = first edge e with erow[e] >= r ----
        const long e0 = ((long)(b - nFeat) * 256 + tid) * 16;
        if (e0 >= E) return;
        int rp = (e0 == 0) ? -1 : erow[e0 - 1];
        if (e0 + 16 <= E) {
            #pragma unroll
            for (int q = 0; q < 4; ++q) {
                const int4 r4 = *(const int4*)(erow + e0 + q * 4);
                const int rs[4] = {r4.x, r4.y, r4.z, r4.w};
                #pragma unroll
                for (int i = 0; i < 4; ++i) {
                    const long e = e0 + q * 4 + i;
                    for (int rr = rp + 1; rr <= rs[i]; ++rr) rptr[rr] = (int)e;
                    rp = rs[i];
                }
            }
            if (e0 + 16 == E) {
                for (int rr = rp + 1; rr <= n; ++rr) rptr[rr] = E;
            }
        } else {
            for (long e = e0; e < E; ++e) {
                const int rb = erow[e];
                for (int rr = rp + 1; rr <= rb; ++rr) rptr[rr] = (int)e;
                rp = rb;
            }
            for (int rr = rp + 1; rr <= n; ++rr) rptr[rr] = E;
        }
        return;
    }

    // ---- feat role ----
    __shared__ unsigned short whS[8192];
    __shared__ unsigned short wlS[8192];
    __shared__ float w1S[128];
    __shared__ float w2S[128];

    // pack W into MFMA B-frag layout (split hi/lo bf16) — whole block
    for (int g = tid; g < 8192; g += 256) {
        const int j = g & 7, lane = (g >> 3) & 63, kc = (g >> 9) & 3, nt = (g >> 11) & 3;
        const int k = kc * 32 + (lane >> 4) * 8 + j;
        const int nn = nt * 16 + (lane & 15);
        const float w = W[k * HIDD + nn];
        const unsigned short hi = f2bf(w);
        whS[g] = hi;
        wlS[g] = f2bf(w - bf2f(hi));
    }
    // w1 = W@a1, w2 = W@a2 (tiny; per-block)
    if (tid < 128) {
        float s = 0.f;
        for (int h = 0; h < HIDD; ++h) s = fmaf(W[tid * HIDD + h], a1[h], s);
        w1S[tid] = s;
    } else {
        const int f = tid - 128;
        float s = 0.f;
        for (int h = 0; h < HIDD; ++h) s = fmaf(W[f * HIDD + h], a2[h], s);
        w2S[f] = s;
    }
    __syncthreads();

    // proven k1 body: fts16 = bf16(seq @ W) via split-bf16 3-term MFMA;
    // f1/f2 fused. One wave = 16 nodes. B-frags/w1/w2 now from LDS.
    const int lane = tid & 63;
    const long wid = (long)b * 4 + (tid >> 6);
    const long n0 = wid * 16;
    if (n0 >= n) return;
    const int m = lane & 15, q = lane >> 4, fb = q * 8;
    long nd = n0 + m; if (nd >= n) nd = n - 1;
    const float* srow = seq + nd * F_INN;

    s8v Ah[4], Al[4];
    float p1 = 0.f, p2 = 0.f;
    #pragma unroll
    for (int kc = 0; kc < 4; ++kc) {
        const v4f r0  = *(const v4f*)(srow + kc * 32 + fb);
        const v4f r1  = *(const v4f*)(srow + kc * 32 + fb + 4);
        const v4f u1a = *(const v4f*)(w1S + kc * 32 + fb);
        const v4f u1b = *(const v4f*)(w1S + kc * 32 + fb + 4);
        const v4f u2a = *(const v4f*)(w2S + kc * 32 + fb);
        const v4f u2b = *(const v4f*)(w2S + kc * 32 + fb + 4);
        #pragma unroll
        for (int j = 0; j < 8; ++j) {
            const float x  = (j < 4) ? r0[j] : r1[j - 4];
            const float wa = (j < 4) ? u1a[j] : u1b[j - 4];
            const float wb = (j < 4) ? u2a[j] : u2b[j - 4];
            const unsigned short h = f2bf(x);
            Ah[kc][j] = (short)h;
            Al[kc][j] = (short)f2bf(x - bf2f(h));
            p1 = fmaf(x, wa, p1);
            p2 = fmaf(x, wb, p2);
        }
    }

    v4f acc[4];
    #pragma unroll
    for (int nt = 0; nt < 4; ++nt) acc[nt] = (v4f){0.f, 0.f, 0.f, 0.f};
    #pragma unroll
    for (int nt = 0; nt < 4; ++nt) {
        #pragma unroll
        for (int kc = 0; kc < 4; ++kc) {
            const int fo = ((nt * 4 + kc) * 64 + lane) * 8;
            const s8v Bh = *(const s8v*)(whS + fo);
            const s8v Bl = *(const s8v*)(wlS + fo);
            acc[nt] = __builtin_amdgcn_mfma_f32_16x16x32_bf16(Ah[kc], Bh, acc[nt], 0, 0, 0);
            acc[nt] = __builtin_amdgcn_mfma_f32_16x16x32_bf16(Ah[kc], Bl, acc[nt], 0, 0, 0);
            acc[nt] = __builtin_amdgcn_mfma_f32_16x16x32_bf16(Al[kc], Bh, acc[nt], 0, 0, 0);
        }
    }

    // C layout: col = lane&15, row = (lane>>4)*4 + reg
    #pragma unroll
    for (int nt = 0; nt < 4; ++nt) {
        #pragma unroll
        for (int reg = 0; reg < 4; ++reg) {
            const long node = n0 + q * 4 + reg;
            if (node < n) fts16[node * HIDD + nt * 16 + m] = f2bf(acc[nt][reg]);
        }
    }
    p1 += __shfl_xor(p1, 16, 64); p1 += __shfl_xor(p1, 32, 64);
    p2 += __shfl_xor(p2, 16, 64); p2 += __shfl_xor(p2, 32, 64);
    if (lane < 16 && n0 + lane < n) {
        f1[n0 + lane] = p1 + b1[0];
        f2[n0 + lane] = p2 + b2[0];
    }
}

// Fast path (deg<=64), R0-proven structure: issue ALL 2*G row-gathers FIRST
// (addresses from LDS-staged cols), pin issue order with sched_barrier(0),
// THEN the f2-dependent leaky/exp work under the gather shadow. z staged to
// LDS, consumed at FMA time; wave_sum(z) runs in the vmem shadow.
template<int G>
__device__ __forceinline__ float fast_path(
    const uint4* __restrict__ fts4, const int* __restrict__ stc,
    float* __restrict__ stz, int lane, int sub, int hc,
    float ev, float f1r, float f2v, float zm, v2f* acc)
{
    uint4 u[2 * G];
    #pragma unroll
    for (int p = 0; p < 2 * G; ++p) u[p] = fts4[stc[p * 8 + sub] + hc];
    __builtin_amdgcn_sched_barrier(0);   // all 2G gathers issued before anything below

    float l = ev * (f1r + f2v);          // waits on f2 only (gathers stay in flight)
    l = (l > 0.f) ? l : ALPHA * l;
    const float z = zm * __expf(l);
    stz[lane] = z;
    float zj[2 * G];
    #pragma unroll
    for (int p = 0; p < 2 * G; ++p) zj[p] = stz[p * 8 + sub];

    #pragma unroll
    for (int p = 0; p < 2 * G; ++p) {
        v2f z2; z2.x = zj[p]; z2.y = zj[p];
        acc[0] = __builtin_elementwise_fma(z2, unpk(u[p].x), acc[0]);
        acc[1] = __builtin_elementwise_fma(z2, unpk(u[p].y), acc[1]);
        acc[2] = __builtin_elementwise_fma(z2, unpk(u[p].z), acc[2]);
        acc[3] = __builtin_elementwise_fma(z2, unpk(u[p].w), acc[3]);
    }
    return wave_sum(z);
}

// Fallback for deg>64 chunks (essentially never hit at E/N=32): 16-edge
// granule, 2 loads in flight.
__device__ __forceinline__ void oct_gather(
    const uint4* __restrict__ fts4, const int* __restrict__ stc,
    const float* __restrict__ stz, int cnt, int sub, int hc, v2f* acc)
{
    const int ngrp = (cnt + 15) >> 4;
    for (int gg = 0; gg < ngrp; ++gg) {
        #pragma unroll
        for (int k = 0; k < 2; ++k) {
            const int idx = (gg * 2 + k) * 8 + sub;
            const uint4 u = fts4[stc[idx] + hc];
            const float zjs = stz[idx];
            v2f z2; z2.x = zjs; z2.y = zjs;
            acc[0] = __builtin_elementwise_fma(z2, unpk(u.x), acc[0]);
            acc[1] = __builtin_elementwise_fma(z2, unpk(u.y), acc[1]);
            acc[2] = __builtin_elementwise_fma(z2, unpk(u.z), acc[2]);
            acc[3] = __builtin_elementwise_fma(z2, unpk(u.w), acc[3]);
        }
    }
}

// K3 (R6/R8-proven best, 62.0us, BYTE-IDENTICAL): one wave per destination
// row; inline z. Chain: rptr -> {ecol,evals} -> [f2 || fts-gathers] -> exp
// -> consume. Many short single-row waves is the verified optimal regime.
// Unnormalized softmax (logits ~N(0,2); algebraically identical).
__global__ __launch_bounds__(256) void k3_attn(
    const int* __restrict__ ecol, const float* __restrict__ evals,
    const int* __restrict__ rptr, const float* __restrict__ f1,
    const float* __restrict__ f2, const uint4* __restrict__ fts4,
    float* __restrict__ out, int n)
{
    __shared__ int   stc[4][64];
    __shared__ float stz[4][64];
    __shared__ float red[4][8][64];
    const int lane = threadIdx.x & 63;
    const int wv = threadIdx.x >> 6;
    const int r = blockIdx.x * 4 + wv;
    if (r >= n) return;
    const int start = rptr[r], end = rptr[r + 1], deg = end - start;
    const float f1r = f1[r];
    const int sub = lane >> 3;   // which edge of the oct
    const int hc  = lane & 7;    // which 16B chunk of the row

    v2f acc[4];
    #pragma unroll
    for (int i = 0; i < 4; ++i) { acc[i].x = 0.f; acc[i].y = 0.f; }
    float s = 0.f;

    if (deg <= 64) {
        const int e = start + lane;
        int c = 0; float ev = 0.f;
        const float zm = (e < end) ? 1.f : 0.f;
        if (e < end) { c = ecol[e]; ev = evals[e]; }
        const float f2v = f2[c];        // random load, issued before the gathers
        stc[wv][lane] = c * 8;          // stage gather addresses immediately
        const int ngrp = (deg + 15) >> 4;   // 0..4, wave-uniform
        switch (ngrp) {
            case 1: s = fast_path<1>(fts4, stc[wv], stz[wv], lane, sub, hc, ev, f1r, f2v, zm, acc); break;
            case 2: s = fast_path<2>(fts4, stc[wv], stz[wv], lane, sub, hc, ev, f1r, f2v, zm, acc); break;
            case 3: s = fast_path<3>(fts4, stc[wv], stz[wv], lane, sub, hc, ev, f1r, f2v, zm, acc); break;
            case 4: s = fast_path<4>(fts4, stc[wv], stz[wv], lane, sub, hc, ev, f1r, f2v, zm, acc); break;
            default: break;   // deg==0: acc=0, s=0 -> out=elu(0)=0, matches ref
        }
    } else {
        for (int base = start; base < end; base += 64) {
            const int e = base + lane;
            int c = 0; float z = 0.f;
            if (e < end) {
                c = ecol[e];
                float l = evals[e] * (f1r + f2[c]);
                l = (l > 0.f) ? l : ALPHA * l;
                z = __expf(l);
            }
            s += z;
            stc[wv][lane] = c * 8;
            stz[wv][lane] = z;
            oct_gather(fts4, stc[wv], stz[wv], min(64, end - base), sub, hc, acc);
        }
        s = wave_sum(s);
    }

    // epilogue: LDS transpose, 8-way sum per feature, ELU, coalesced store.
    float* rd = &red[wv][0][0];
    *(v4f*)(rd + sub * 64 + hc * 8)     = (v4f){acc[0].x, acc[0].y, acc[1].x, acc[1].y};
    *(v4f*)(rd + sub * 64 + hc * 8 + 4) = (v4f){acc[2].x, acc[2].y, acc[3].x, acc[3].y};
    const float inv = (deg > 0) ? __builtin_amdgcn_rcpf(s) : 0.f;
    float t = 0.f;
    #pragma unroll
    for (int i = 0; i < 8; ++i) t += rd[i * 64 + lane];
    float v = t * inv;
    v = (v > 0.f) ? v : (__expf(v) - 1.f);
    out[(size_t)r * HIDD + lane] = v;
}

extern "C" void kernel_launch(void* const* d_in, const int* in_sizes, int n_in,
                              void* d_out, int out_size, void* d_ws, size_t ws_size,
                              hipStream_t stream)
{
    const float* seq   = (const float*)d_in[0];
    const int*   erow  = (const int*)  d_in[1];
    const int*   ecol  = (const int*)  d_in[2];
    const float* evals = (const float*)d_in[3];
    const float* W     = (const float*)d_in[4];
    const float* a1    = (const float*)d_in[5];
    const float* b1    = (const float*)d_in[6];
    const float* a2    = (const float*)d_in[7];
    const float* b2    = (const float*)d_in[8];
    // d_in[9] = bias_zero (zeros) — additive no-op, skipped.

    const int N = in_sizes[0] / F_INN;
    const int E = in_sizes[1];

    // workspace: fts16 | f1 | f2 | rptr  (~14 MB)
    char* p = (char*)d_ws;
    unsigned short* fts16 = (unsigned short*)p; p += (size_t)N * HIDD * 2;
    float* f1 = (float*)p; p += (size_t)N * 4;
    float* f2 = (float*)p; p += (size_t)N * 4;
    int* rptr = (int*)p;   p += (size_t)(N + 1) * 4;

    float* out = (float*)d_out;

    const int waves1  = (N + 15) / 16;
    const int nFeat   = (waves1 + 3) / 4;          // 1563
    const int nScat   = (E + 4095) / 4096;         // 782 (16 edges/thread)
    k01_feat<<<nFeat + nScat, 256, 0, stream>>>(seq, W, a1, a2, b1, b2, erow,
                                                fts16, f1, f2, rptr, N, E, nFeat);

    const int blocks3 = (N + 3) / 4;
    k3_attn<<<blocks3, 256, 0, stream>>>(ecol, evals, rptr, f1, f2,
                                         (const uint4*)fts16, out, N);
}

// Round 10
// 200.504 us; speedup vs baseline: 1.0405x; 1.0405x over previous
//
#include <hip/hip_runtime.h>
#include <math.h>
#include <stdint.h>

#define F_INN 128
#define HIDD 64
#define ALPHA 0.2f

typedef float v4f  __attribute__((ext_vector_type(4)));
typedef float v2f  __attribute__((ext_vector_type(2)));
typedef short s8v  __attribute__((ext_vector_type(8)));

__device__ __forceinline__ float wave_sum(float v) {
    #pragma unroll
    for (int m = 32; m >= 1; m >>= 1) v += __shfl_xor(v, m, 64);
    return v;
}
// fp32 -> bf16 (RNE) and back
__device__ __forceinline__ unsigned short f2bf(float f) {
    unsigned u = __float_as_uint(f);
    return (unsigned short)((u + 0x7FFFu + ((u >> 16) & 1u)) >> 16);
}
__device__ __forceinline__ float bf2f(unsigned short h) {
    return __uint_as_float(((unsigned)h) << 16);
}
// unpack 2 bf16 (packed in a uint) -> v2f  (2 VALU)
__device__ __forceinline__ v2f unpk(unsigned u) {
    const uint2 t = make_uint2(u << 16, u & 0xFFFF0000u);
    v2f r; r.x = __uint_as_float(t.x); r.y = __uint_as_float(t.y);
    return r;
}

// K02: block 0 -> w1=W@a1, w2=W@a2; blocks 1..32 -> pack W into MFMA B-frag
// layout (split hi/lo bf16); blocks 33+ -> rptr via boundary scatter over
// EDGES (one coalesced pass; cheaper than the 22-probe dependent binary
// search). Exact R6/R8 configuration, twice measured at 201.3/201.5us total.
// NOTE (R9): merging this into k1 costs +7us (1563x redundant W-pack) —
// per-kernel launch overhead is NOT the residual; don't re-try.
__global__ void k02_prep(const float* __restrict__ W, const float* __restrict__ a1,
                         const float* __restrict__ a2, const int* __restrict__ erow,
                         float* __restrict__ w1, float* __restrict__ w2,
                         unsigned short* __restrict__ whF, unsigned short* __restrict__ wlF,
                         int* __restrict__ rptr, int n, int E)
{
    const int tid = threadIdx.x, b = blockIdx.x;
    if (b == 0) {
        if (tid < 128) {
            float s = 0.f;
            for (int h = 0; h < HIDD; ++h) s = fmaf(W[tid * HIDD + h], a1[h], s);
            w1[tid] = s;
        } else {
            const int f = tid - 128;
            float s = 0.f;
            for (int h = 0; h < HIDD; ++h) s = fmaf(W[f * HIDD + h], a2[h], s);
            w2[f] = s;
        }
        return;
    }
    if (b <= 32) {
        const int g = (b - 1) * 256 + tid;   // 32*256 = 8192
        const int j = g & 7, lane = (g >> 3) & 63, kc = (g >> 9) & 3, nt = (g >> 11) & 3;
        const int k = kc * 32 + (lane >> 4) * 8 + j;
        const int nn = nt * 16 + (lane & 15);
        const float w = W[k * HIDD + nn];
        const unsigned short hi = f2bf(w);
        whF[g] = hi;
        wlF[g] = f2bf(w - bf2f(hi));
        return;
    }
    // rptr[r] = first edge index e with erow[e] >= r  (erow sorted ascending)
    const long e = (long)(b - 33) * 256 + tid;
    if (e >= E) return;
    const int rb = erow[e];
    const int ra = (e == 0) ? -1 : erow[e - 1];
    for (int r = ra + 1; r <= rb; ++r) rptr[r] = (int)e;
    if (e == E - 1) {
        for (int r = rb + 1; r <= n; ++r) rptr[r] = E;
    }
}

// K1: fts16 = bf16(seq @ W) via split-bf16 3-term MFMA (fp32-accurate);
// f1/f2 fused. One wave = 16 nodes, direct global A-frag loads.
// At its ~64 MB memory floor — do not touch.
__global__ __launch_bounds__(256) void k1_feat(
    const float* __restrict__ seq,
    const unsigned short* __restrict__ whF, const unsigned short* __restrict__ wlF,
    const float* __restrict__ w1, const float* __restrict__ w2,
    const float* __restrict__ b1, const float* __restrict__ b2,
    unsigned short* __restrict__ fts16, float* __restrict__ f1, float* __restrict__ f2,
    int n)
{
    const int lane = threadIdx.x & 63;
    const long wid = blockIdx.x * 4 + (threadIdx.x >> 6);
    const long n0 = wid * 16;
    if (n0 >= n) return;
    const int m = lane & 15, q = lane >> 4, fb = q * 8;
    long nd = n0 + m; if (nd >= n) nd = n - 1;
    const float* srow = seq + nd * F_INN;

    s8v Ah[4], Al[4];
    float p1 = 0.f, p2 = 0.f;
    #pragma unroll
    for (int kc = 0; kc < 4; ++kc) {
        const v4f r0  = *(const v4f*)(srow + kc * 32 + fb);
        const v4f r1  = *(const v4f*)(srow + kc * 32 + fb + 4);
        const v4f u1a = *(const v4f*)(w1 + kc * 32 + fb);
        const v4f u1b = *(const v4f*)(w1 + kc * 32 + fb + 4);
        const v4f u2a = *(const v4f*)(w2 + kc * 32 + fb);
        const v4f u2b = *(const v4f*)(w2 + kc * 32 + fb + 4);
        #pragma unroll
        for (int j = 0; j < 8; ++j) {
            const float x  = (j < 4) ? r0[j] : r1[j - 4];
            const float wa = (j < 4) ? u1a[j] : u1b[j - 4];
            const float wb = (j < 4) ? u2a[j] : u2b[j - 4];
            const unsigned short h = f2bf(x);
            Ah[kc][j] = (short)h;
            Al[kc][j] = (short)f2bf(x - bf2f(h));
            p1 = fmaf(x, wa, p1);
            p2 = fmaf(x, wb, p2);
        }
    }

    v4f acc[4];
    #pragma unroll
    for (int nt = 0; nt < 4; ++nt) acc[nt] = (v4f){0.f, 0.f, 0.f, 0.f};
    #pragma unroll
    for (int nt = 0; nt < 4; ++nt) {
        #pragma unroll
        for (int kc = 0; kc < 4; ++kc) {
            const int fo = ((nt * 4 + kc) * 64 + lane) * 8;
            const s8v Bh = *(const s8v*)(whF + fo);
            const s8v Bl = *(const s8v*)(wlF + fo);
            acc[nt] = __builtin_amdgcn_mfma_f32_16x16x32_bf16(Ah[kc], Bh, acc[nt], 0, 0, 0);
            acc[nt] = __builtin_amdgcn_mfma_f32_16x16x32_bf16(Ah[kc], Bl, acc[nt], 0, 0, 0);
            acc[nt] = __builtin_amdgcn_mfma_f32_16x16x32_bf16(Al[kc], Bh, acc[nt], 0, 0, 0);
        }
    }

    // C layout: col = lane&15, row = (lane>>4)*4 + reg
    #pragma unroll
    for (int nt = 0; nt < 4; ++nt) {
        #pragma unroll
        for (int reg = 0; reg < 4; ++reg) {
            const long node = n0 + q * 4 + reg;
            if (node < n) fts16[node * HIDD + nt * 16 + m] = f2bf(acc[nt][reg]);
        }
    }
    p1 += __shfl_xor(p1, 16, 64); p1 += __shfl_xor(p1, 32, 64);
    p2 += __shfl_xor(p2, 16, 64); p2 += __shfl_xor(p2, 32, 64);
    if (lane < 16 && n0 + lane < n) {
        f1[n0 + lane] = p1 + b1[0];
        f2[n0 + lane] = p2 + b2[0];
    }
}

// Fast path (deg<=64), R0-proven structure: issue ALL 2*G row-gathers FIRST
// (addresses from LDS-staged cols), pin issue order with sched_barrier(0),
// THEN the f2-dependent leaky/exp work under the gather shadow. z staged to
// LDS, consumed at FMA time; wave_sum(z) runs in the vmem shadow.
template<int G>
__device__ __forceinline__ float fast_path(
    const uint4* __restrict__ fts4, const int* __restrict__ stc,
    float* __restrict__ stz, int lane, int sub, int hc,
    float ev, float f1r, float f2v, float zm, v2f* acc)
{
    uint4 u[2 * G];
    #pragma unroll
    for (int p = 0; p < 2 * G; ++p) u[p] = fts4[stc[p * 8 + sub] + hc];
    __builtin_amdgcn_sched_barrier(0);   // all 2G gathers issued before anything below

    float l = ev * (f1r + f2v);          // waits on f2 only (gathers stay in flight)
    l = (l > 0.f) ? l : ALPHA * l;
    const float z = zm * __expf(l);
    stz[lane] = z;
    float zj[2 * G];
    #pragma unroll
    for (int p = 0; p < 2 * G; ++p) zj[p] = stz[p * 8 + sub];

    #pragma unroll
    for (int p = 0; p < 2 * G; ++p) {
        v2f z2; z2.x = zj[p]; z2.y = zj[p];
        acc[0] = __builtin_elementwise_fma(z2, unpk(u[p].x), acc[0]);
        acc[1] = __builtin_elementwise_fma(z2, unpk(u[p].y), acc[1]);
        acc[2] = __builtin_elementwise_fma(z2, unpk(u[p].z), acc[2]);
        acc[3] = __builtin_elementwise_fma(z2, unpk(u[p].w), acc[3]);
    }
    return wave_sum(z);
}

// Fallback for deg>64 chunks (essentially never hit at E/N=32): 16-edge
// granule, 2 loads in flight.
__device__ __forceinline__ void oct_gather(
    const uint4* __restrict__ fts4, const int* __restrict__ stc,
    const float* __restrict__ stz, int cnt, int sub, int hc, v2f* acc)
{
    const int ngrp = (cnt + 15) >> 4;
    for (int gg = 0; gg < ngrp; ++gg) {
        #pragma unroll
        for (int k = 0; k < 2; ++k) {
            const int idx = (gg * 2 + k) * 8 + sub;
            const uint4 u = fts4[stc[idx] + hc];
            const float zjs = stz[idx];
            v2f z2; z2.x = zjs; z2.y = zjs;
            acc[0] = __builtin_elementwise_fma(z2, unpk(u.x), acc[0]);
            acc[1] = __builtin_elementwise_fma(z2, unpk(u.y), acc[1]);
            acc[2] = __builtin_elementwise_fma(z2, unpk(u.z), acc[2]);
            acc[3] = __builtin_elementwise_fma(z2, unpk(u.w), acc[3]);
        }
    }
}

// K3 (R6/R8-proven best, 62.0us): one wave per destination row; inline z.
// Chain: rptr -> {ecol,evals} -> [f2 || fts-gathers] -> exp -> consume.
// Many short single-row waves is the verified optimal regime (R2/R3/R7).
// Unnormalized softmax (logits ~N(0,2); algebraically identical).
__global__ __launch_bounds__(256) void k3_attn(
    const int* __restrict__ ecol, const float* __restrict__ evals,
    const int* __restrict__ rptr, const float* __restrict__ f1,
    const float* __restrict__ f2, const uint4* __restrict__ fts4,
    float* __restrict__ out, int n)
{
    __shared__ int   stc[4][64];
    __shared__ float stz[4][64];
    __shared__ float red[4][8][64];
    const int lane = threadIdx.x & 63;
    const int wv = threadIdx.x >> 6;
    const int r = blockIdx.x * 4 + wv;
    if (r >= n) return;
    const int start = rptr[r], end = rptr[r + 1], deg = end - start;
    const float f1r = f1[r];
    const int sub = lane >> 3;   // which edge of the oct
    const int hc  = lane & 7;    // which 16B chunk of the row

    v2f acc[4];
    #pragma unroll
    for (int i = 0; i < 4; ++i) { acc[i].x = 0.f; acc[i].y = 0.f; }
    float s = 0.f;

    if (deg <= 64) {
        const int e = start + lane;
        int c = 0; float ev = 0.f;
        const float zm = (e < end) ? 1.f : 0.f;
        if (e < end) { c = ecol[e]; ev = evals[e]; }
        const float f2v = f2[c];        // random load, issued before the gathers
        stc[wv][lane] = c * 8;          // stage gather addresses immediately
        const int ngrp = (deg + 15) >> 4;   // 0..4, wave-uniform
        switch (ngrp) {
            case 1: s = fast_path<1>(fts4, stc[wv], stz[wv], lane, sub, hc, ev, f1r, f2v, zm, acc); break;
            case 2: s = fast_path<2>(fts4, stc[wv], stz[wv], lane, sub, hc, ev, f1r, f2v, zm, acc); break;
            case 3: s = fast_path<3>(fts4, stc[wv], stz[wv], lane, sub, hc, ev, f1r, f2v, zm, acc); break;
            case 4: s = fast_path<4>(fts4, stc[wv], stz[wv], lane, sub, hc, ev, f1r, f2v, zm, acc); break;
            default: break;   // deg==0: acc=0, s=0 -> out=elu(0)=0, matches ref
        }
    } else {
        for (int base = start; base < end; base += 64) {
            const int e = base + lane;
            int c = 0; float z = 0.f;
            if (e < end) {
                c = ecol[e];
                float l = evals[e] * (f1r + f2[c]);
                l = (l > 0.f) ? l : ALPHA * l;
                z = __expf(l);
            }
            s += z;
            stc[wv][lane] = c * 8;
            stz[wv][lane] = z;
            oct_gather(fts4, stc[wv], stz[wv], min(64, end - base), sub, hc, acc);
        }
        s = wave_sum(s);
    }

    // epilogue: LDS transpose, 8-way sum per feature, ELU, coalesced store.
    float* rd = &red[wv][0][0];
    *(v4f*)(rd + sub * 64 + hc * 8)     = (v4f){acc[0].x, acc[0].y, acc[1].x, acc[1].y};
    *(v4f*)(rd + sub * 64 + hc * 8 + 4) = (v4f){acc[2].x, acc[2].y, acc[3].x, acc[3].y};
    const float inv = (deg > 0) ? __builtin_amdgcn_rcpf(s) : 0.f;
    float t = 0.f;
    #pragma unroll
    for (int i = 0; i < 8; ++i) t += rd[i * 64 + lane];
    float v = t * inv;
    v = (v > 0.f) ? v : (__expf(v) - 1.f);
    out[(size_t)r * HIDD + lane] = v;
}

extern "C" void kernel_launch(void* const* d_in, const int* in_sizes, int n_in,
                              void* d_out, int out_size, void* d_ws, size_t ws_size,
                              hipStream_t stream)
{
    const float* seq   = (const float*)d_in[0];
    const int*   erow  = (const int*)  d_in[1];
    const int*   ecol  = (const int*)  d_in[2];
    const float* evals = (const float*)d_in[3];
    const float* W     = (const float*)d_in[4];
    const float* a1    = (const float*)d_in[5];
    const float* b1    = (const float*)d_in[6];
    const float* a2    = (const float*)d_in[7];
    const float* b2    = (const float*)d_in[8];
    // d_in[9] = bias_zero (zeros) — additive no-op, skipped.

    const int N = in_sizes[0] / F_INN;
    const int E = in_sizes[1];

    // workspace: fts16 | f1 | f2 | rptr | w1 | w2 | whF | wlF  (~14.1 MB)
    char* p = (char*)d_ws;
    unsigned short* fts16 = (unsigned short*)p; p += (size_t)N * HIDD * 2;
    float* f1 = (float*)p; p += (size_t)N * 4;
    float* f2 = (float*)p; p += (size_t)N * 4;
    int* rptr = (int*)p;   p += (size_t)(N + 1) * 4;
    p = (char*)(((uintptr_t)p + 15) & ~(uintptr_t)15);
    float* w1 = (float*)p; p += 128 * 4;
    float* w2 = (float*)p; p += 128 * 4;
    unsigned short* whF = (unsigned short*)p; p += 8192 * 2;
    unsigned short* wlF = (unsigned short*)p;

    float* out = (float*)d_out;

    const int eblocks = (E + 255) / 256;
    k02_prep<<<33 + eblocks, 256, 0, stream>>>(W, a1, a2, erow, w1, w2,
                                               whF, wlF, rptr, N, E);

    const int waves1  = (N + 15) / 16;
    const int blocks1 = (waves1 + 3) / 4;
    k1_feat<<<blocks1, 256, 0, stream>>>(seq, whF, wlF, w1, w2, b1, b2,
                                         fts16, f1, f2, N);

    const int blocks3 = (N + 3) / 4;
    k3_attn<<<blocks3, 256, 0, stream>>>(ecol, evals, rptr, f1, f2,
                                         (const uint4*)fts16, out, N);
}